// Round 12
// baseline (631.465 us; speedup 1.0000x reference)
//
#include <hip/hip_runtime.h>
#include <hip/hip_bf16.h>

// GCN attention forward, MI355X. *** DIAGNOSTIC ROUND (REP=2) ***
// R9-R11: all kernels dropped below the 77us harness-fill line -> top-5 gives
// no counters; 3 rounds of blind tuning gained only 8%. This round each kernel
// repeats its body twice (idempotent rewrites, graph-safe) so k1/k2/k3 exceed
// the fill line and report full counters. dur regresses BY DESIGN (~450us);
// next round uses the counters to attack the real sink.

#define NN    4096
#define ROWS  8192
#define OFT   256
#define CAP   128
#define NBLK  512
#define RPB   16
#define REP   2
#define EPSN  1e-12f
#define MFMA(a,b,c) __builtin_amdgcn_mfma_f32_16x16x32_bf16((a),(b),(c),0,0,0)

typedef unsigned short ushort_t;
typedef __attribute__((ext_vector_type(8))) short bf16x8;
typedef __attribute__((ext_vector_type(4))) float f32x4;

// Wp: bf16 weights in k-major frag layout, frag (col,k8c) at (k8c*256+col)*8.
#define WP_FC   0
#define WP_Q    (16384 * 8)
#define WP_K    (WP_Q + 8192 * 8)
#define WP_V1   (WP_K + 8192 * 8)
#define WP_V2   (WP_V1 + 8192 * 8)

__device__ __forceinline__ float lo_f(unsigned u) { union { unsigned i; float f; } c; c.i = u << 16;          return c.f; }
__device__ __forceinline__ float hi_f(unsigned u) { union { unsigned i; float f; } c; c.i = u & 0xFFFF0000u;  return c.f; }
__device__ __forceinline__ float bf2f(ushort_t u) { union { unsigned i; float f; } c; c.i = (unsigned)u << 16; return c.f; }
__device__ __forceinline__ ushort_t f2bf(float f) {
    union { float f; unsigned i; } c; c.f = f;
    unsigned r = c.i + 0x7FFFu + ((c.i >> 16) & 1u);
    return (ushort_t)(r >> 16);
}
__device__ __forceinline__ unsigned pack2(float a, float b) {
    return (unsigned)f2bf(a) | ((unsigned)f2bf(b) << 16);
}

__device__ __forceinline__ int detect32(const unsigned* w, int tid, int* scnt)
{
    if (tid == 0) *scnt = 0;
    __syncthreads();
    if (tid < 256) {
        union { unsigned i; float f; } c; c.i = w[tid];
        float a = fabsf(c.f);
        if (a > 1e-4f && a < 0.5f) atomicAdd(scnt, 1);
    }
    __syncthreads();
    return *scnt >= 128;
}

// ===================== k0: weight prep -> bf16 frag layout ==================
__global__ __launch_bounds__(256) void k0_prep(
    const void* __restrict__ Wfc, const void* __restrict__ Wq,
    const void* __restrict__ Wk,  const void* __restrict__ Wv1,
    const void* __restrict__ Wv2, ushort_t* __restrict__ Wp)
{
    __shared__ int scnt;
    const int tid = threadIdx.x;
    const int is32 = detect32((const unsigned*)Wfc, tid, &scnt);
    int sid = blockIdx.x * 256 + tid;
    const void* src; int K, local; ushort_t* dst;
    if (sid < 16384) { src = Wfc; K = 512; local = sid; dst = Wp + WP_FC + (size_t)local * 8; }
    else {
        int s = sid - 16384, which = s >> 13; local = s & 8191;
        const void* ws4[4] = {Wq, Wk, Wv1, Wv2};
        src = ws4[which]; K = 256;
        dst = Wp + WP_Q + (size_t)which * 65536 + (size_t)local * 8;
    }
    int col = local & 255, k8c = local >> 8;
    if (is32) {
        const float* p = (const float*)src + (size_t)col * K + k8c * 8;
        float4 x0 = *(const float4*)p, x1 = *(const float4*)(p + 4);
        uint4 o; o.x = pack2(x0.x, x0.y); o.y = pack2(x0.z, x0.w);
        o.z = pack2(x1.x, x1.y); o.w = pack2(x1.z, x1.w);
        *(uint4*)dst = o;
    } else {
        *(bf16x8*)dst = *(const bf16x8*)((const ushort_t*)src + (size_t)col * K + k8c * 8);
    }
}

// ============================ k1: extract + fc ==============================
__global__ __launch_bounds__(1024, 8) void k1_extract_fc(
    const void* __restrict__ seq, const void* __restrict__ adj,
    const void* __restrict__ Wfc, const ushort_t* __restrict__ Wp,
    ushort_t* __restrict__ regA, unsigned* __restrict__ gcv,
    int* __restrict__ cnt)
{
    __shared__ ushort_t Astage[64 * 17 * 8];
    __shared__ unsigned csr_cv[RPB * CAP];
    __shared__ int      csr_n[RPB];
    __shared__ int      scnt;

    const int tid = threadIdx.x, wave = tid >> 6, lane = tid & 63;
    const int t16 = lane & 15, kq = lane >> 4;
    const int b = blockIdx.x, r0 = b * RPB;

    const int is32 = detect32((const unsigned*)Wfc, tid, &scnt);

    for (int rep = 0; rep < REP; ++rep) {       // DIAGNOSTIC repeat
    // ---- extract: wave -> row `wave`, 4 chunks of 4 vec4-slots per lane
    {
        const int rl = wave;
        const size_t grow = (size_t)(r0 + rl);
        int base = 0;
        if (is32) {
            const float4* rowp = (const float4*)((const float*)adj + grow * NN);
            for (int h = 0; h < 4; ++h) {
                float4 v[4];
#pragma unroll
                for (int t = 0; t < 4; ++t) v[t] = rowp[(h * 4 + t) * 64 + lane];
                int c = 0;
#pragma unroll
                for (int t = 0; t < 4; ++t)
                    c += (v[t].x > 0.f) + (v[t].y > 0.f) + (v[t].z > 0.f) + (v[t].w > 0.f);
                int incl = c;
#pragma unroll
                for (int off = 1; off < 64; off <<= 1) {
                    int y = __shfl_up(incl, off, 64);
                    if (lane >= off) incl += y;
                }
                int p = base + incl - c;
                base += __shfl(incl, 63, 64);
#pragma unroll
                for (int t = 0; t < 4; ++t) {
                    float f[4] = {v[t].x, v[t].y, v[t].z, v[t].w};
#pragma unroll
                    for (int j = 0; j < 4; ++j)
                        if (f[j] > 0.f) {
                            if (p < CAP) {
                                unsigned col = ((h * 4 + t) * 64 + lane) * 4 + j;
                                csr_cv[rl * CAP + p] = (col << 16) | f2bf(f[j]);
                            }
                            ++p;
                        }
                }
            }
        } else {
            const uint2* rowp = (const uint2*)((const ushort_t*)adj + grow * NN);
            for (int h = 0; h < 4; ++h) {
                uint2 v[4];
#pragma unroll
                for (int t = 0; t < 4; ++t) v[t] = rowp[(h * 4 + t) * 64 + lane];
                int c = 0;
#pragma unroll
                for (int t = 0; t < 4; ++t)
                    c += (lo_f(v[t].x) > 0.f) + (hi_f(v[t].x) > 0.f)
                       + (lo_f(v[t].y) > 0.f) + (hi_f(v[t].y) > 0.f);
                int incl = c;
#pragma unroll
                for (int off = 1; off < 64; off <<= 1) {
                    int y = __shfl_up(incl, off, 64);
                    if (lane >= off) incl += y;
                }
                int p = base + incl - c;
                base += __shfl(incl, 63, 64);
#pragma unroll
                for (int t = 0; t < 4; ++t) {
                    ushort_t raw[4] = {(ushort_t)(v[t].x & 0xFFFF), (ushort_t)(v[t].x >> 16),
                                       (ushort_t)(v[t].y & 0xFFFF), (ushort_t)(v[t].y >> 16)};
#pragma unroll
                    for (int j = 0; j < 4; ++j)
                        if (bf2f(raw[j]) > 0.f) {
                            if (p < CAP) {
                                unsigned col = ((h * 4 + t) * 64 + lane) * 4 + j;
                                csr_cv[rl * CAP + p] = (col << 16) | raw[j];
                            }
                            ++p;
                        }
                }
            }
        }
        if (lane == 0) csr_n[rl] = (base < CAP) ? base : CAP;
    }
    __syncthreads();
    for (int i = tid; i < RPB * CAP; i += 1024)
        gcv[b * (RPB * CAP) + i] = csr_cv[i];
    if (tid < RPB) cnt[r0 + tid] = csr_n[tid];

    // ---- stage seq 16 x 512
    {
        int row = tid >> 6, seg = tid & 63;
        bf16x8 f0;
        if (is32) {
            const float* p = (const float*)seq + (size_t)(r0 + row) * 512 + seg * 8;
            float4 x0 = *(const float4*)p, x1 = *(const float4*)(p + 4);
            uint4 a;
            a.x = pack2(x0.x, x0.y); a.y = pack2(x0.z, x0.w);
            a.z = pack2(x1.x, x1.y); a.w = pack2(x1.z, x1.w);
            f0 = *(bf16x8*)&a;
        } else {
            f0 = *(const bf16x8*)((const ushort_t*)seq + (size_t)(r0 + row) * 512 + seg * 8);
        }
        *(bf16x8*)(Astage + ((size_t)seg * 17 + row) * 8) = f0;
    }
    __syncthreads();

    // ---- fc GEMM: wave -> 16 cols, 16 k-chunks, batched frag loads
    {
        const int col = wave * 16 + t16;
        const ushort_t* Wm = Wp + WP_FC;
        f32x4 a0 = {0.f, 0.f, 0.f, 0.f};
        for (int bch = 0; bch < 4; ++bch) {
            bf16x8 wb[4];
#pragma unroll
            for (int c2 = 0; c2 < 4; ++c2) {
                int k8c = (bch * 4 + c2) * 4 + kq;
                wb[c2] = *(const bf16x8*)(Wm + ((size_t)k8c * 256 + col) * 8);
            }
#pragma unroll
            for (int c2 = 0; c2 < 4; ++c2) {
                int c = bch * 4 + c2;
                bf16x8 af = *(const bf16x8*)(Astage + ((size_t)(c * 4 + kq) * 17 + t16) * 8);
                a0 = MFMA(af, wb[c2], a0);
            }
        }
#pragma unroll
        for (int r = 0; r < 4; ++r)
            regA[(size_t)(r0 + kq * 4 + r) * OFT + col] = f2bf(a0[r]);
    }
    __syncthreads();        // rep boundary
    }
}

// ===================== k2: spmm + q/k GEMM + norm + loss ====================
__global__ __launch_bounds__(512) void k2_spmm_qk(
    const ushort_t* __restrict__ regA, ushort_t* __restrict__ regKO,
    ushort_t* __restrict__ regQ, const ushort_t* __restrict__ Wp,
    const unsigned* __restrict__ gcv, const int* __restrict__ cnt,
    float* __restrict__ part)
{
    __shared__ ushort_t Astage[32 * 17 * 8];
    __shared__ unsigned csr_cv[RPB * CAP];
    __shared__ ushort_t qn_l[RPB * OFT];
    __shared__ float    red[2][RPB][4];
    __shared__ float    dlred[8];

    const int tid = threadIdx.x, wave = tid >> 6, lane = tid & 63;
    const int t16 = lane & 15, kq = lane >> 4;
    const int b = blockIdx.x, r0 = b * RPB;
    const size_t batb = (size_t)(b >> 8) * 4096;

    for (int i = tid; i < RPB * CAP; i += 512)
        csr_cv[i] = gcv[b * (RPB * CAP) + i];
    __syncthreads();

    for (int rep = 0; rep < REP; ++rep) {       // DIAGNOSTIC repeat
    // ---- spmm, software-pipelined
    {
        const int rA = wave * 2, rB = rA + 1;
        const int nA = cnt[r0 + rA], nB = cnt[r0 + rB];
        const int nm = max(nA, nB);
        const ushort_t* gA = regA + batb * OFT;
        float a0[4] = {0,0,0,0}, a1[4] = {0,0,0,0};
        unsigned cvA = 0, cvB = 0;
        uint2 uA = {0, 0}, uB = {0, 0};
        if (0 < nA) { cvA = csr_cv[rA*CAP]; uA = *(const uint2*)(gA + (size_t)(cvA >> 16) * OFT + lane * 4); }
        if (0 < nB) { cvB = csr_cv[rB*CAP]; uB = *(const uint2*)(gA + (size_t)(cvB >> 16) * OFT + lane * 4); }
        for (int i = 0; i < nm; ++i) {
            unsigned cvA1 = 0, cvB1 = 0;
            uint2 uA1 = {0, 0}, uB1 = {0, 0};
            if (i + 1 < nA) { cvA1 = csr_cv[rA*CAP + i + 1]; uA1 = *(const uint2*)(gA + (size_t)(cvA1 >> 16) * OFT + lane * 4); }
            if (i + 1 < nB) { cvB1 = csr_cv[rB*CAP + i + 1]; uB1 = *(const uint2*)(gA + (size_t)(cvB1 >> 16) * OFT + lane * 4); }
            if (i < nA) {
                float vv = bf2f((ushort_t)(cvA & 0xFFFF));
                a0[0]+=vv*lo_f(uA.x); a0[1]+=vv*hi_f(uA.x); a0[2]+=vv*lo_f(uA.y); a0[3]+=vv*hi_f(uA.y);
            }
            if (i < nB) {
                float vv = bf2f((ushort_t)(cvB & 0xFFFF));
                a1[0]+=vv*lo_f(uB.x); a1[1]+=vv*hi_f(uB.x); a1[2]+=vv*lo_f(uB.y); a1[3]+=vv*hi_f(uB.y);
            }
            cvA = cvA1; uA = uA1; cvB = cvB1; uB = uB1;
        }
        uint2 s0; s0.x = pack2(a0[0], a0[1]); s0.y = pack2(a0[2], a0[3]);
        uint2 s1; s1.x = pack2(a1[0], a1[1]); s1.y = pack2(a1[2], a1[3]);
        *(uint2*)(regKO + (size_t)(r0 + rA) * 512 + lane * 8 + 4) = s0;
        *(uint2*)(regKO + (size_t)(r0 + rB) * 512 + lane * 8 + 4) = s1;
        *(uint2*)(Astage + ((lane >> 1) * 17 + rA) * 8 + (lane & 1) * 4) = s0;
        *(uint2*)(Astage + ((lane >> 1) * 17 + rB) * 8 + (lane & 1) * 4) = s1;
    }
    __syncthreads();

    // ---- q/k GEMM (waves 0-3: q, 4-7: k)
    {
    const int isK = wave >> 2, w4 = wave & 3;
    const ushort_t* Wm = Wp + (isK ? WP_K : WP_Q);
    f32x4 acc[4];
#pragma unroll
    for (int j = 0; j < 4; ++j) acc[j] = (f32x4){0.f,0.f,0.f,0.f};
    for (int bch = 0; bch < 4; ++bch) {
        bf16x8 wb[4][2];
#pragma unroll
        for (int j = 0; j < 4; ++j)
#pragma unroll
            for (int c2 = 0; c2 < 2; ++c2) {
                int col = w4 * 64 + j * 16 + t16;
                int k8c = (bch * 2 + c2) * 4 + kq;
                wb[j][c2] = *(const bf16x8*)(Wm + ((size_t)k8c * 256 + col) * 8);
            }
#pragma unroll
        for (int c2 = 0; c2 < 2; ++c2) {
            int c = bch * 2 + c2;
            bf16x8 af = *(const bf16x8*)(Astage + ((c*4 + kq) * 17 + t16) * 8);
#pragma unroll
            for (int j = 0; j < 4; ++j) acc[j] = MFMA(af, wb[j][c2], acc[j]);
        }
    }
#pragma unroll
    for (int r = 0; r < 4; ++r) {
        float s = 0.f;
#pragma unroll
        for (int j = 0; j < 4; ++j) s += acc[j][r] * acc[j][r];
#pragma unroll
        for (int off = 1; off < 16; off <<= 1) s += __shfl_xor(s, off, 16);
        if (t16 == 0) red[isK][kq*4 + r][w4] = s;
    }
    __syncthreads();
#pragma unroll
    for (int r = 0; r < 4; ++r) {
        int row = kq * 4 + r;
        float s = red[isK][row][0] + red[isK][row][1] + red[isK][row][2] + red[isK][row][3];
        float inv = 1.f / fmaxf(sqrtf(s), EPSN);
#pragma unroll
        for (int j = 0; j < 4; ++j) {
            int col = w4 * 64 + j * 16 + t16;
            float v = acc[j][r] * inv;
            acc[j][r] = v;
            ushort_t uv = f2bf(v);
            if (isK) regKO[(size_t)(r0 + row) * 512 + (col >> 2) * 8 + (col & 3)] = uv;
            else { qn_l[row * OFT + col] = uv; regQ[(size_t)(r0 + row) * OFT + col] = uv; }
        }
    }
    __syncthreads();
    if (isK) {
        float dl = 0.f;
#pragma unroll
        for (int r = 0; r < 4; ++r) {
            int row = kq * 4 + r;
#pragma unroll
            for (int j = 0; j < 4; ++j) {
                int col = w4 * 64 + j * 16 + t16;
                float d = bf2f(qn_l[row * OFT + col]) - acc[j][r];
                dl += d * d;
            }
        }
#pragma unroll
        for (int off = 1; off < 64; off <<= 1) dl += __shfl_xor(dl, off, 64);
        if (lane == 0) dlred[wave] = dl;
    }
    __syncthreads();
    if (tid == 0) part[b] = dlred[4] + dlred[5] + dlred[6] + dlred[7];
    }
    __syncthreads();        // rep boundary
    }
}

// ========================= k3: attn + v1 + v2 ==============================
__global__ __launch_bounds__(512) void k3_attn_v(
    const ushort_t* __restrict__ regKO, const ushort_t* __restrict__ regQ,
    const unsigned* __restrict__ gcv, const int* __restrict__ cnt,
    const ushort_t* __restrict__ Wp, const void* __restrict__ Wfc,
    const void* __restrict__ a_v, const void* __restrict__ a_act,
    const void* __restrict__ biasv, const float* __restrict__ part,
    void* __restrict__ out)
{
    __shared__ ushort_t Astage[32 * 17 * 8];
    __shared__ ushort_t Hl[32 * 17 * 8];
    __shared__ unsigned csr_cv[RPB * CAP];
    __shared__ float    s8[8];
    __shared__ int      scnt;

    const int tid = threadIdx.x, wave = tid >> 6, lane = tid & 63;
    const int t16 = lane & 15, kq = lane >> 4;
    const int b = blockIdx.x, r0 = b * RPB;
    const size_t batb = (size_t)(b >> 8) * 4096;

    const int is32 = detect32((const unsigned*)Wfc, tid, &scnt);

    if (b == 0) {
        float s = part[tid];
#pragma unroll
        for (int off = 32; off; off >>= 1) s += __shfl_down(s, off, 64);
        if (lane == 0) s8[wave] = s;
        __syncthreads();
        if (tid == 0) {
            float t = s8[0]+s8[1]+s8[2]+s8[3]+s8[4]+s8[5]+s8[6]+s8[7];
            float v = t * (1.f / 8192.f);
            if (is32) ((float*)out)[(size_t)ROWS * OFT] = v;
            else      ((ushort_t*)out)[(size_t)ROWS * OFT] = f2bf(v);
        }
    }

    for (int i = tid; i < RPB * CAP; i += 512)
        csr_cv[i] = gcv[b * (RPB * CAP) + i];
    __syncthreads();

    for (int rep = 0; rep < REP; ++rep) {       // DIAGNOSTIC repeat
    // ---- attention: ONE uint4 gather per edge, pipelined
    {
        const int rA = wave * 2, rB = rA + 1;
        const int nA = cnt[r0 + rA], nB = cnt[r0 + rB];
        const int nm = max(nA, nB);
        uint2 qa = *(const uint2*)(regQ + (size_t)(r0 + rA) * OFT + lane * 4);
        uint2 qb = *(const uint2*)(regQ + (size_t)(r0 + rB) * OFT + lane * 4);
        float qA[4] = {lo_f(qa.x), hi_f(qa.x), lo_f(qa.y), hi_f(qa.y)};
        float qB[4] = {lo_f(qb.x), hi_f(qb.x), lo_f(qb.y), hi_f(qb.y)};
        const ushort_t* gKO = regKO + batb * 512;
        float sA = 0.f, sB = 0.f;
        float cA[4] = {0,0,0,0}, cB[4] = {0,0,0,0};
        uint4 vA = {0,0,0,0}, vB = {0,0,0,0};
        if (0 < nA) vA = *(const uint4*)(gKO + (size_t)(csr_cv[rA*CAP] >> 16) * 512 + lane * 8);
        if (0 < nB) vB = *(const uint4*)(gKO + (size_t)(csr_cv[rB*CAP] >> 16) * 512 + lane * 8);
        for (int i = 0; i < nm; ++i) {
            uint4 vA1 = {0,0,0,0}, vB1 = {0,0,0,0};
            if (i + 1 < nA) vA1 = *(const uint4*)(gKO + (size_t)(csr_cv[rA*CAP + i + 1] >> 16) * 512 + lane * 8);
            if (i + 1 < nB) vB1 = *(const uint4*)(gKO + (size_t)(csr_cv[rB*CAP + i + 1] >> 16) * 512 + lane * 8);
            if (i < nA) {
                float d = lo_f(vA.x)*qA[0] + hi_f(vA.x)*qA[1] + lo_f(vA.y)*qA[2] + hi_f(vA.y)*qA[3];
#pragma unroll
                for (int off = 1; off < 64; off <<= 1) d += __shfl_xor(d, off, 64);
                float es = __expf(d);
                sA += es;
                cA[0]+=es*lo_f(vA.z); cA[1]+=es*hi_f(vA.z); cA[2]+=es*lo_f(vA.w); cA[3]+=es*hi_f(vA.w);
            }
            if (i < nB) {
                float d = lo_f(vB.x)*qB[0] + hi_f(vB.x)*qB[1] + lo_f(vB.y)*qB[2] + hi_f(vB.y)*qB[3];
#pragma unroll
                for (int off = 1; off < 64; off <<= 1) d += __shfl_xor(d, off, 64);
                float es = __expf(d);
                sB += es;
                cB[0]+=es*lo_f(vB.z); cB[1]+=es*hi_f(vB.z); cB[2]+=es*lo_f(vB.w); cB[3]+=es*hi_f(vB.w);
            }
            vA = vA1; vB = vB1;
        }
        float iA = 1.f / sA, iB = 1.f / sB;
        uint2 s0; s0.x = pack2(cA[0]*iA, cA[1]*iA); s0.y = pack2(cA[2]*iA, cA[3]*iA);
        uint2 s1; s1.x = pack2(cB[0]*iB, cB[1]*iB); s1.y = pack2(cB[2]*iB, cB[3]*iB);
        *(uint2*)(Astage + ((lane >> 1) * 17 + rA) * 8 + (lane & 1) * 4) = s0;
        *(uint2*)(Astage + ((lane >> 1) * 17 + rB) * 8 + (lane & 1) * 4) = s1;
    }
    __syncthreads();

    // ---- v1 GEMM + PReLU(a_v) -> Hl (k-major)
    const int col0 = wave * 32 + t16, col1 = col0 + 16;
    {
        const ushort_t* Wm = Wp + WP_V1;
        f32x4 h0 = {0.f,0.f,0.f,0.f}, h1 = {0.f,0.f,0.f,0.f};
        for (int bch = 0; bch < 2; ++bch) {
            bf16x8 wb0[4], wb1[4];
#pragma unroll
            for (int c2 = 0; c2 < 4; ++c2) {
                int k8c = (bch * 4 + c2) * 4 + kq;
                wb0[c2] = *(const bf16x8*)(Wm + ((size_t)k8c * 256 + col0) * 8);
                wb1[c2] = *(const bf16x8*)(Wm + ((size_t)k8c * 256 + col1) * 8);
            }
#pragma unroll
            for (int c2 = 0; c2 < 4; ++c2) {
                int c = bch * 4 + c2;
                bf16x8 af = *(const bf16x8*)(Astage + ((c*4 + kq) * 17 + t16) * 8);
                h0 = MFMA(af, wb0[c2], h0);
                h1 = MFMA(af, wb1[c2], h1);
            }
        }
        float av = is32 ? *(const float*)a_v : bf2f(*(const ushort_t*)a_v);
        int q0 = col0 >> 3, off0 = col0 & 7, q1 = col1 >> 3;
#pragma unroll
        for (int r = 0; r < 4; ++r) {
            int row = kq * 4 + r;
            float x0 = h0[r]; x0 = (x0 >= 0.f) ? x0 : av * x0;
            float x1 = h1[r]; x1 = (x1 >= 0.f) ? x1 : av * x1;
            Hl[(q0 * 17 + row) * 8 + off0] = f2bf(x0);
            Hl[(q1 * 17 + row) * 8 + off0] = f2bf(x1);
        }
    }
    __syncthreads();

    // ---- v2 GEMM + bias + PReLU(a_act) -> out
    {
        const ushort_t* Wm = Wp + WP_V2;
        f32x4 y0 = {0.f,0.f,0.f,0.f}, y1 = {0.f,0.f,0.f,0.f};
        for (int bch = 0; bch < 2; ++bch) {
            bf16x8 wb0[4], wb1[4];
#pragma unroll
            for (int c2 = 0; c2 < 4; ++c2) {
                int k8c = (bch * 4 + c2) * 4 + kq;
                wb0[c2] = *(const bf16x8*)(Wm + ((size_t)k8c * 256 + col0) * 8);
                wb1[c2] = *(const bf16x8*)(Wm + ((size_t)k8c * 256 + col1) * 8);
            }
#pragma unroll
            for (int c2 = 0; c2 < 4; ++c2) {
                int c = bch * 4 + c2;
                bf16x8 af = *(const bf16x8*)(Hl + ((c*4 + kq) * 17 + t16) * 8);
                y0 = MFMA(af, wb0[c2], y0);
                y1 = MFMA(af, wb1[c2], y1);
            }
        }
        float aa = is32 ? *(const float*)a_act : bf2f(*(const ushort_t*)a_act);
        float bv0 = is32 ? ((const float*)biasv)[col0] : bf2f(((const ushort_t*)biasv)[col0]);
        float bv1 = is32 ? ((const float*)biasv)[col1] : bf2f(((const ushort_t*)biasv)[col1]);
#pragma unroll
        for (int r = 0; r < 4; ++r) {
            size_t row = (size_t)(r0 + kq * 4 + r);
            float x0 = y0[r] + bv0; x0 = (x0 >= 0.f) ? x0 : aa * x0;
            float x1 = y1[r] + bv1; x1 = (x1 >= 0.f) ? x1 : aa * x1;
            if (is32) {
                ((float*)out)[row * OFT + col0] = x0;
                ((float*)out)[row * OFT + col1] = x1;
            } else {
                ((ushort_t*)out)[row * OFT + col0] = f2bf(x0);
                ((ushort_t*)out)[row * OFT + col1] = f2bf(x1);
            }
        }
    }
    __syncthreads();        // rep boundary
    }
}

// ------------------------------------------------------------------- launch
extern "C" void kernel_launch(void* const* d_in, const int* in_sizes, int n_in,
                              void* d_out, int out_size, void* d_ws, size_t ws_size,
                              hipStream_t stream)
{
    const void* seq   = d_in[0];
    const void* adj   = d_in[1];
    const void* W_fc  = d_in[2];
    const void* W_q   = d_in[3];
    const void* W_k   = d_in[4];
    const void* W_v1  = d_in[5];
    const void* W_v2  = d_in[6];
    const void* a_v   = d_in[7];
    const void* a_act = d_in[8];
    const void* bias  = d_in[9];

    char* w = (char*)d_ws;
    ushort_t* regA  = (ushort_t*)w;
    ushort_t* regKO = (ushort_t*)(w + (4u  << 20));
    ushort_t* regQ  = (ushort_t*)(w + (12u << 20));
    unsigned* gcv   = (unsigned*)(w + (16u << 20));
    int*      cnt   = (int*)(w + (20u << 20));
    float*    part  = (float*)(w + (20u << 20) + 32768);
    ushort_t* Wp    = (ushort_t*)(w + (21u << 20));

    k0_prep<<<192, 256, 0, stream>>>(W_fc, W_q, W_k, W_v1, W_v2, Wp);
    k1_extract_fc<<<NBLK, 1024, 0, stream>>>(seq, adj, W_fc, Wp, regA, gcv, cnt);
    k2_spmm_qk<<<NBLK, 512, 0, stream>>>(regA, regKO, regQ, Wp, gcv, cnt, part);
    k3_attn_v<<<NBLK, 512, 0, stream>>>(regKO, regQ, gcv, cnt, Wp,
                                        W_fc, a_v, a_act, bias, part, d_out);
}

// Round 13
// 296.107 us; speedup vs baseline: 2.1326x; 2.1326x over previous
//
#include <hip/hip_runtime.h>
#include <hip/hip_bf16.h>

// GCN attention forward, MI355X. R12 diagnostic: k3 attention = 107us of the
// ~160us kernel total; sink = per-edge 6-step 64-lane shfl butterfly (LDS-pipe
// serialization). Fix: k3a = 16-lane-per-edge attention with pure-VALU DPP
// reductions (quad_perm xor1/xor2 + row_ror:4/8), 4 edges in flight per wave,
// branchless predication; cross-lane shuffles only ONCE per row. v1/v2 GEMMs
// split to k3b. k0/k1/k2 unchanged from R11 (REP removed).

#define NN    4096
#define ROWS  8192
#define OFT   256
#define CAP   128
#define NBLK  512
#define RPB   16
#define EPSN  1e-12f
#define MFMA(a,b,c) __builtin_amdgcn_mfma_f32_16x16x32_bf16((a),(b),(c),0,0,0)

typedef unsigned short ushort_t;
typedef __attribute__((ext_vector_type(8))) short bf16x8;
typedef __attribute__((ext_vector_type(4))) float f32x4;

#define WP_FC   0
#define WP_Q    (16384 * 8)
#define WP_K    (WP_Q + 8192 * 8)
#define WP_V1   (WP_K + 8192 * 8)
#define WP_V2   (WP_V1 + 8192 * 8)

__device__ __forceinline__ float lo_f(unsigned u) { union { unsigned i; float f; } c; c.i = u << 16;          return c.f; }
__device__ __forceinline__ float hi_f(unsigned u) { union { unsigned i; float f; } c; c.i = u & 0xFFFF0000u;  return c.f; }
__device__ __forceinline__ float bf2f(ushort_t u) { union { unsigned i; float f; } c; c.i = (unsigned)u << 16; return c.f; }
__device__ __forceinline__ ushort_t f2bf(float f) {
    union { float f; unsigned i; } c; c.f = f;
    unsigned r = c.i + 0x7FFFu + ((c.i >> 16) & 1u);
    return (ushort_t)(r >> 16);
}
__device__ __forceinline__ unsigned pack2(float a, float b) {
    return (unsigned)f2bf(a) | ((unsigned)f2bf(b) << 16);
}

// VALU-only partial-sum exchange: x + dpp_mov(x). CTRL: 0xB1=quad xor1,
// 0x4E=quad xor2, 0x124=row_ror:4, 0x128=row_ror:8. After all four, every
// lane of each 16-lane row holds the 16-lane sum. No LDS pipe involved.
template<int CTRL>
__device__ __forceinline__ float dpp_add(float x) {
    union { float f; int i; } c; c.f = x;
    int y = __builtin_amdgcn_update_dpp(c.i, c.i, CTRL, 0xF, 0xF, false);
    union { int i; float f; } r; r.i = y;
    return x + r.f;
}

__device__ __forceinline__ int detect32(const unsigned* w, int tid, int* scnt)
{
    if (tid == 0) *scnt = 0;
    __syncthreads();
    if (tid < 256) {
        union { unsigned i; float f; } c; c.i = w[tid];
        float a = fabsf(c.f);
        if (a > 1e-4f && a < 0.5f) atomicAdd(scnt, 1);
    }
    __syncthreads();
    return *scnt >= 128;
}

// ===================== k0: weight prep -> bf16 frag layout ==================
__global__ __launch_bounds__(256) void k0_prep(
    const void* __restrict__ Wfc, const void* __restrict__ Wq,
    const void* __restrict__ Wk,  const void* __restrict__ Wv1,
    const void* __restrict__ Wv2, ushort_t* __restrict__ Wp)
{
    __shared__ int scnt;
    const int tid = threadIdx.x;
    const int is32 = detect32((const unsigned*)Wfc, tid, &scnt);
    int sid = blockIdx.x * 256 + tid;
    const void* src; int K, local; ushort_t* dst;
    if (sid < 16384) { src = Wfc; K = 512; local = sid; dst = Wp + WP_FC + (size_t)local * 8; }
    else {
        int s = sid - 16384, which = s >> 13; local = s & 8191;
        const void* ws4[4] = {Wq, Wk, Wv1, Wv2};
        src = ws4[which]; K = 256;
        dst = Wp + WP_Q + (size_t)which * 65536 + (size_t)local * 8;
    }
    int col = local & 255, k8c = local >> 8;
    if (is32) {
        const float* p = (const float*)src + (size_t)col * K + k8c * 8;
        float4 x0 = *(const float4*)p, x1 = *(const float4*)(p + 4);
        uint4 o; o.x = pack2(x0.x, x0.y); o.y = pack2(x0.z, x0.w);
        o.z = pack2(x1.x, x1.y); o.w = pack2(x1.z, x1.w);
        *(uint4*)dst = o;
    } else {
        *(bf16x8*)dst = *(const bf16x8*)((const ushort_t*)src + (size_t)col * K + k8c * 8);
    }
}

// ============================ k1: extract + fc ==============================
__global__ __launch_bounds__(1024, 8) void k1_extract_fc(
    const void* __restrict__ seq, const void* __restrict__ adj,
    const void* __restrict__ Wfc, const ushort_t* __restrict__ Wp,
    ushort_t* __restrict__ regA, unsigned* __restrict__ gcv,
    int* __restrict__ cnt)
{
    __shared__ ushort_t Astage[64 * 17 * 8];
    __shared__ unsigned csr_cv[RPB * CAP];
    __shared__ int      csr_n[RPB];
    __shared__ int      scnt;

    const int tid = threadIdx.x, wave = tid >> 6, lane = tid & 63;
    const int t16 = lane & 15, kq = lane >> 4;
    const int b = blockIdx.x, r0 = b * RPB;

    const int is32 = detect32((const unsigned*)Wfc, tid, &scnt);

    {   // extract: wave -> row `wave`, per-lane count + wave prefix scan
        const int rl = wave;
        const size_t grow = (size_t)(r0 + rl);
        int base = 0;
        if (is32) {
            const float4* rowp = (const float4*)((const float*)adj + grow * NN);
            for (int h = 0; h < 4; ++h) {
                float4 v[4];
#pragma unroll
                for (int t = 0; t < 4; ++t) v[t] = rowp[(h * 4 + t) * 64 + lane];
                int c = 0;
#pragma unroll
                for (int t = 0; t < 4; ++t)
                    c += (v[t].x > 0.f) + (v[t].y > 0.f) + (v[t].z > 0.f) + (v[t].w > 0.f);
                int incl = c;
#pragma unroll
                for (int off = 1; off < 64; off <<= 1) {
                    int y = __shfl_up(incl, off, 64);
                    if (lane >= off) incl += y;
                }
                int p = base + incl - c;
                base += __shfl(incl, 63, 64);
#pragma unroll
                for (int t = 0; t < 4; ++t) {
                    float f[4] = {v[t].x, v[t].y, v[t].z, v[t].w};
#pragma unroll
                    for (int j = 0; j < 4; ++j)
                        if (f[j] > 0.f) {
                            if (p < CAP) {
                                unsigned col = ((h * 4 + t) * 64 + lane) * 4 + j;
                                csr_cv[rl * CAP + p] = (col << 16) | f2bf(f[j]);
                            }
                            ++p;
                        }
                }
            }
        } else {
            const uint2* rowp = (const uint2*)((const ushort_t*)adj + grow * NN);
            for (int h = 0; h < 4; ++h) {
                uint2 v[4];
#pragma unroll
                for (int t = 0; t < 4; ++t) v[t] = rowp[(h * 4 + t) * 64 + lane];
                int c = 0;
#pragma unroll
                for (int t = 0; t < 4; ++t)
                    c += (lo_f(v[t].x) > 0.f) + (hi_f(v[t].x) > 0.f)
                       + (lo_f(v[t].y) > 0.f) + (hi_f(v[t].y) > 0.f);
                int incl = c;
#pragma unroll
                for (int off = 1; off < 64; off <<= 1) {
                    int y = __shfl_up(incl, off, 64);
                    if (lane >= off) incl += y;
                }
                int p = base + incl - c;
                base += __shfl(incl, 63, 64);
#pragma unroll
                for (int t = 0; t < 4; ++t) {
                    ushort_t raw[4] = {(ushort_t)(v[t].x & 0xFFFF), (ushort_t)(v[t].x >> 16),
                                       (ushort_t)(v[t].y & 0xFFFF), (ushort_t)(v[t].y >> 16)};
#pragma unroll
                    for (int j = 0; j < 4; ++j)
                        if (bf2f(raw[j]) > 0.f) {
                            if (p < CAP) {
                                unsigned col = ((h * 4 + t) * 64 + lane) * 4 + j;
                                csr_cv[rl * CAP + p] = (col << 16) | raw[j];
                            }
                            ++p;
                        }
                }
            }
        }
        if (lane == 0) csr_n[rl] = (base < CAP) ? base : CAP;
    }
    __syncthreads();
    for (int i = tid; i < RPB * CAP; i += 1024)
        gcv[b * (RPB * CAP) + i] = csr_cv[i];
    if (tid < RPB) cnt[r0 + tid] = csr_n[tid];

    {   // stage seq 16 x 512
        int row = tid >> 6, seg = tid & 63;
        bf16x8 f0;
        if (is32) {
            const float* p = (const float*)seq + (size_t)(r0 + row) * 512 + seg * 8;
            float4 x0 = *(const float4*)p, x1 = *(const float4*)(p + 4);
            uint4 a;
            a.x = pack2(x0.x, x0.y); a.y = pack2(x0.z, x0.w);
            a.z = pack2(x1.x, x1.y); a.w = pack2(x1.z, x1.w);
            f0 = *(bf16x8*)&a;
        } else {
            f0 = *(const bf16x8*)((const ushort_t*)seq + (size_t)(r0 + row) * 512 + seg * 8);
        }
        *(bf16x8*)(Astage + ((size_t)seg * 17 + row) * 8) = f0;
    }
    __syncthreads();

    {   // fc GEMM
        const int col = wave * 16 + t16;
        const ushort_t* Wm = Wp + WP_FC;
        f32x4 a0 = {0.f, 0.f, 0.f, 0.f};
        for (int bch = 0; bch < 4; ++bch) {
            bf16x8 wb[4];
#pragma unroll
            for (int c2 = 0; c2 < 4; ++c2) {
                int k8c = (bch * 4 + c2) * 4 + kq;
                wb[c2] = *(const bf16x8*)(Wm + ((size_t)k8c * 256 + col) * 8);
            }
#pragma unroll
            for (int c2 = 0; c2 < 4; ++c2) {
                int c = bch * 4 + c2;
                bf16x8 af = *(const bf16x8*)(Astage + ((size_t)(c * 4 + kq) * 17 + t16) * 8);
                a0 = MFMA(af, wb[c2], a0);
            }
        }
#pragma unroll
        for (int r = 0; r < 4; ++r)
            regA[(size_t)(r0 + kq * 4 + r) * OFT + col] = f2bf(a0[r]);
    }
}

// ===================== k2: spmm + q/k GEMM + norm + loss ====================
__global__ __launch_bounds__(512) void k2_spmm_qk(
    const ushort_t* __restrict__ regA, ushort_t* __restrict__ regKO,
    ushort_t* __restrict__ regQ, const ushort_t* __restrict__ Wp,
    const unsigned* __restrict__ gcv, const int* __restrict__ cnt,
    float* __restrict__ part)
{
    __shared__ ushort_t Astage[32 * 17 * 8];
    __shared__ unsigned csr_cv[RPB * CAP];
    __shared__ ushort_t qn_l[RPB * OFT];
    __shared__ float    red[2][RPB][4];
    __shared__ float    dlred[8];

    const int tid = threadIdx.x, wave = tid >> 6, lane = tid & 63;
    const int t16 = lane & 15, kq = lane >> 4;
    const int b = blockIdx.x, r0 = b * RPB;
    const size_t batb = (size_t)(b >> 8) * 4096;

    for (int i = tid; i < RPB * CAP; i += 512)
        csr_cv[i] = gcv[b * (RPB * CAP) + i];
    __syncthreads();

    {   // spmm, software-pipelined
        const int rA = wave * 2, rB = rA + 1;
        const int nA = cnt[r0 + rA], nB = cnt[r0 + rB];
        const int nm = max(nA, nB);
        const ushort_t* gA = regA + batb * OFT;
        float a0[4] = {0,0,0,0}, a1[4] = {0,0,0,0};
        unsigned cvA = 0, cvB = 0;
        uint2 uA = {0, 0}, uB = {0, 0};
        if (0 < nA) { cvA = csr_cv[rA*CAP]; uA = *(const uint2*)(gA + (size_t)(cvA >> 16) * OFT + lane * 4); }
        if (0 < nB) { cvB = csr_cv[rB*CAP]; uB = *(const uint2*)(gA + (size_t)(cvB >> 16) * OFT + lane * 4); }
        for (int i = 0; i < nm; ++i) {
            unsigned cvA1 = 0, cvB1 = 0;
            uint2 uA1 = {0, 0}, uB1 = {0, 0};
            if (i + 1 < nA) { cvA1 = csr_cv[rA*CAP + i + 1]; uA1 = *(const uint2*)(gA + (size_t)(cvA1 >> 16) * OFT + lane * 4); }
            if (i + 1 < nB) { cvB1 = csr_cv[rB*CAP + i + 1]; uB1 = *(const uint2*)(gA + (size_t)(cvB1 >> 16) * OFT + lane * 4); }
            if (i < nA) {
                float vv = bf2f((ushort_t)(cvA & 0xFFFF));
                a0[0]+=vv*lo_f(uA.x); a0[1]+=vv*hi_f(uA.x); a0[2]+=vv*lo_f(uA.y); a0[3]+=vv*hi_f(uA.y);
            }
            if (i < nB) {
                float vv = bf2f((ushort_t)(cvB & 0xFFFF));
                a1[0]+=vv*lo_f(uB.x); a1[1]+=vv*hi_f(uB.x); a1[2]+=vv*lo_f(uB.y); a1[3]+=vv*hi_f(uB.y);
            }
            cvA = cvA1; uA = uA1; cvB = cvB1; uB = uB1;
        }
        uint2 s0; s0.x = pack2(a0[0], a0[1]); s0.y = pack2(a0[2], a0[3]);
        uint2 s1; s1.x = pack2(a1[0], a1[1]); s1.y = pack2(a1[2], a1[3]);
        *(uint2*)(regKO + (size_t)(r0 + rA) * 512 + lane * 8 + 4) = s0;
        *(uint2*)(regKO + (size_t)(r0 + rB) * 512 + lane * 8 + 4) = s1;
        *(uint2*)(Astage + ((lane >> 1) * 17 + rA) * 8 + (lane & 1) * 4) = s0;
        *(uint2*)(Astage + ((lane >> 1) * 17 + rB) * 8 + (lane & 1) * 4) = s1;
    }
    __syncthreads();

    // q/k GEMM (waves 0-3: q, 4-7: k)
    const int isK = wave >> 2, w4 = wave & 3;
    const ushort_t* Wm = Wp + (isK ? WP_K : WP_Q);
    f32x4 acc[4];
#pragma unroll
    for (int j = 0; j < 4; ++j) acc[j] = (f32x4){0.f,0.f,0.f,0.f};
    for (int bch = 0; bch < 4; ++bch) {
        bf16x8 wb[4][2];
#pragma unroll
        for (int j = 0; j < 4; ++j)
#pragma unroll
            for (int c2 = 0; c2 < 2; ++c2) {
                int col = w4 * 64 + j * 16 + t16;
                int k8c = (bch * 2 + c2) * 4 + kq;
                wb[j][c2] = *(const bf16x8*)(Wm + ((size_t)k8c * 256 + col) * 8);
            }
#pragma unroll
        for (int c2 = 0; c2 < 2; ++c2) {
            int c = bch * 2 + c2;
            bf16x8 af = *(const bf16x8*)(Astage + ((c*4 + kq) * 17 + t16) * 8);
#pragma unroll
            for (int j = 0; j < 4; ++j) acc[j] = MFMA(af, wb[j][c2], acc[j]);
        }
    }
#pragma unroll
    for (int r = 0; r < 4; ++r) {
        float s = 0.f;
#pragma unroll
        for (int j = 0; j < 4; ++j) s += acc[j][r] * acc[j][r];
#pragma unroll
        for (int off = 1; off < 16; off <<= 1) s += __shfl_xor(s, off, 16);
        if (t16 == 0) red[isK][kq*4 + r][w4] = s;
    }
    __syncthreads();
#pragma unroll
    for (int r = 0; r < 4; ++r) {
        int row = kq * 4 + r;
        float s = red[isK][row][0] + red[isK][row][1] + red[isK][row][2] + red[isK][row][3];
        float inv = 1.f / fmaxf(sqrtf(s), EPSN);
#pragma unroll
        for (int j = 0; j < 4; ++j) {
            int col = w4 * 64 + j * 16 + t16;
            float v = acc[j][r] * inv;
            acc[j][r] = v;
            ushort_t uv = f2bf(v);
            if (isK) regKO[(size_t)(r0 + row) * 512 + (col >> 2) * 8 + (col & 3)] = uv;
            else { qn_l[row * OFT + col] = uv; regQ[(size_t)(r0 + row) * OFT + col] = uv; }
        }
    }
    __syncthreads();
    if (isK) {
        float dl = 0.f;
#pragma unroll
        for (int r = 0; r < 4; ++r) {
            int row = kq * 4 + r;
#pragma unroll
            for (int j = 0; j < 4; ++j) {
                int col = w4 * 64 + j * 16 + t16;
                float d = bf2f(qn_l[row * OFT + col]) - acc[j][r];
                dl += d * d;
            }
        }
#pragma unroll
        for (int off = 1; off < 64; off <<= 1) dl += __shfl_xor(dl, off, 64);
        if (lane == 0) dlred[wave] = dl;
    }
    __syncthreads();
    if (tid == 0) part[b] = dlred[4] + dlred[5] + dlred[6] + dlred[7];
}

// ================= k3a: attention, DPP reductions, 4 edges/wave =============
// Wave -> one row. Lane = (grp, t16): grp = edge slot (4 concurrent), t16
// owns dims 16*t16..+15. Per edge: 4 uint4 loads (kn|outb interleaved KO),
// 16-FMA dot, 4 DPP adds (VALU-only 16-lane reduce), exp, 16-FMA ctx acc.
// Cross-group + denom reduce: once per row (xor16/32).
__global__ __launch_bounds__(512) void k3a_attn(
    const ushort_t* __restrict__ regKO, const ushort_t* __restrict__ regQ,
    ushort_t* __restrict__ ctxG, const unsigned* __restrict__ gcv,
    const int* __restrict__ cnt)
{
    __shared__ unsigned csr_cv[8 * CAP];
    const int tid = threadIdx.x, wave = tid >> 6, lane = tid & 63;
    const int t16 = lane & 15, grp = lane >> 4;
    const int b = blockIdx.x, r0 = b * 8;
    const size_t batb = (size_t)(b >> 9) * 4096;   // 512 blocks per batch

    for (int i = tid; i < 8 * CAP; i += 512)
        csr_cv[i] = gcv[(size_t)r0 * CAP + i];
    __syncthreads();

    const int row = r0 + wave;
    const int n = cnt[row];

    float q[16];
    {
        const ushort_t* qp = regQ + (size_t)row * OFT + t16 * 16;
        uint4 a = *(const uint4*)qp, bq = *(const uint4*)(qp + 8);
        unsigned uu[8] = {a.x, a.y, a.z, a.w, bq.x, bq.y, bq.z, bq.w};
#pragma unroll
        for (int j = 0; j < 8; ++j) { q[2*j] = lo_f(uu[j]); q[2*j+1] = hi_f(uu[j]); }
    }

    const ushort_t* gKO = regKO + batb * 512;
    float c[16];
#pragma unroll
    for (int j = 0; j < 16; ++j) c[j] = 0.f;
    float sE = 0.f;

    const int nIter = (n + 3) >> 2;
    for (int it = 0; it < nIter; ++it) {
        int e = it * 4 + grp;
        int valid = (e < n);
        unsigned cv = csr_cv[wave * CAP + (valid ? e : 0)];
        const ushort_t* p = gKO + (size_t)(cv >> 16) * 512 + t16 * 32;
        uint4 v[4];
#pragma unroll
        for (int i2 = 0; i2 < 4; ++i2) v[i2] = *(const uint4*)(p + i2 * 8);
        float d = 0.f;
#pragma unroll
        for (int i2 = 0; i2 < 4; ++i2)
            d += q[4*i2+0]*lo_f(v[i2].x) + q[4*i2+1]*hi_f(v[i2].x)
               + q[4*i2+2]*lo_f(v[i2].y) + q[4*i2+3]*hi_f(v[i2].y);
        // 16-lane sum, VALU-only (all lanes active -> DPP-safe)
        d = dpp_add<0xB1>(d);    // quad xor1
        d = dpp_add<0x4E>(d);    // quad xor2
        d = dpp_add<0x124>(d);   // row_ror:4
        d = dpp_add<0x128>(d);   // row_ror:8
        float es = __expf(d);    // |d|<=1: no max-subtraction
        es = valid ? es : 0.f;
        sE += es;
#pragma unroll
        for (int i2 = 0; i2 < 4; ++i2) {
            c[4*i2+0] += es * lo_f(v[i2].z); c[4*i2+1] += es * hi_f(v[i2].z);
            c[4*i2+2] += es * lo_f(v[i2].w); c[4*i2+3] += es * hi_f(v[i2].w);
        }
    }
    // cross-group reduce, once per row
#pragma unroll
    for (int j = 0; j < 16; ++j) {
        c[j] += __shfl_xor(c[j], 16, 64);
        c[j] += __shfl_xor(c[j], 32, 64);
    }
    sE += __shfl_xor(sE, 16, 64);
    sE += __shfl_xor(sE, 32, 64);
    float inv = 1.f / sE;
    {   // group g writes dims t16*16 + g*4..+3 -> contiguous 512B per row
        int d0 = grp * 4;
        uint2 st; st.x = pack2(c[d0]*inv, c[d0+1]*inv);
        st.y = pack2(c[d0+2]*inv, c[d0+3]*inv);
        *(uint2*)(ctxG + (size_t)row * OFT + t16 * 16 + d0) = st;
    }
}

// ===================== k3b: v1 + v2 GEMMs (+ loss finalize) =================
__global__ __launch_bounds__(512) void k3b_v(
    const ushort_t* __restrict__ ctxG, const ushort_t* __restrict__ Wp,
    const void* __restrict__ Wfc, const void* __restrict__ a_v,
    const void* __restrict__ a_act, const void* __restrict__ biasv,
    const float* __restrict__ part, void* __restrict__ out)
{
    __shared__ ushort_t Astage[32 * 17 * 8];
    __shared__ ushort_t Hl[32 * 17 * 8];
    __shared__ float    s8[8];
    __shared__ int      scnt;

    const int tid = threadIdx.x, wave = tid >> 6, lane = tid & 63;
    const int t16 = lane & 15, kq = lane >> 4;
    const int b = blockIdx.x, r0 = b * RPB;

    const int is32 = detect32((const unsigned*)Wfc, tid, &scnt);

    if (b == 0) {      // div_loss finalize (512 partials from k2)
        float s = part[tid];
#pragma unroll
        for (int off = 32; off; off >>= 1) s += __shfl_down(s, off, 64);
        if (lane == 0) s8[wave] = s;
        __syncthreads();
        if (tid == 0) {
            float t = s8[0]+s8[1]+s8[2]+s8[3]+s8[4]+s8[5]+s8[6]+s8[7];
            float v = t * (1.f / 8192.f);
            if (is32) ((float*)out)[(size_t)ROWS * OFT] = v;
            else      ((ushort_t*)out)[(size_t)ROWS * OFT] = f2bf(v);
        }
    }

    {   // stage ctx 16 x 256 -> k-major frag layout
        int row = tid >> 5, q0 = tid & 31;
        bf16x8 f0 = *(const bf16x8*)(ctxG + (size_t)(r0 + row) * OFT + q0 * 8);
        *(bf16x8*)(Astage + ((size_t)q0 * 17 + row) * 8) = f0;
    }
    __syncthreads();

    const int col0 = wave * 32 + t16, col1 = col0 + 16;
    {   // v1 GEMM + PReLU(a_v) -> Hl
        const ushort_t* Wm = Wp + WP_V1;
        f32x4 h0 = {0.f,0.f,0.f,0.f}, h1 = {0.f,0.f,0.f,0.f};
        for (int bch = 0; bch < 2; ++bch) {
            bf16x8 wb0[4], wb1[4];
#pragma unroll
            for (int c2 = 0; c2 < 4; ++c2) {
                int k8c = (bch * 4 + c2) * 4 + kq;
                wb0[c2] = *(const bf16x8*)(Wm + ((size_t)k8c * 256 + col0) * 8);
                wb1[c2] = *(const bf16x8*)(Wm + ((size_t)k8c * 256 + col1) * 8);
            }
#pragma unroll
            for (int c2 = 0; c2 < 4; ++c2) {
                int c = bch * 4 + c2;
                bf16x8 af = *(const bf16x8*)(Astage + ((c*4 + kq) * 17 + t16) * 8);
                h0 = MFMA(af, wb0[c2], h0);
                h1 = MFMA(af, wb1[c2], h1);
            }
        }
        float av = is32 ? *(const float*)a_v : bf2f(*(const ushort_t*)a_v);
        int q0 = col0 >> 3, off0 = col0 & 7, q1 = col1 >> 3;
#pragma unroll
        for (int r = 0; r < 4; ++r) {
            int row = kq * 4 + r;
            float x0 = h0[r]; x0 = (x0 >= 0.f) ? x0 : av * x0;
            float x1 = h1[r]; x1 = (x1 >= 0.f) ? x1 : av * x1;
            Hl[(q0 * 17 + row) * 8 + off0] = f2bf(x0);
            Hl[(q1 * 17 + row) * 8 + off0] = f2bf(x1);
        }
    }
    __syncthreads();

    {   // v2 GEMM + bias + PReLU(a_act) -> out
        const ushort_t* Wm = Wp + WP_V2;
        f32x4 y0 = {0.f,0.f,0.f,0.f}, y1 = {0.f,0.f,0.f,0.f};
        for (int bch = 0; bch < 2; ++bch) {
            bf16x8 wb0[4], wb1[4];
#pragma unroll
            for (int c2 = 0; c2 < 4; ++c2) {
                int k8c = (bch * 4 + c2) * 4 + kq;
                wb0[c2] = *(const bf16x8*)(Wm + ((size_t)k8c * 256 + col0) * 8);
                wb1[c2] = *(const bf16x8*)(Wm + ((size_t)k8c * 256 + col1) * 8);
            }
#pragma unroll
            for (int c2 = 0; c2 < 4; ++c2) {
                int c = bch * 4 + c2;
                bf16x8 af = *(const bf16x8*)(Hl + ((c*4 + kq) * 17 + t16) * 8);
                y0 = MFMA(af, wb0[c2], y0);
                y1 = MFMA(af, wb1[c2], y1);
            }
        }
        float aa = is32 ? *(const float*)a_act : bf2f(*(const ushort_t*)a_act);
        float bv0 = is32 ? ((const float*)biasv)[col0] : bf2f(((const ushort_t*)biasv)[col0]);
        float bv1 = is32 ? ((const float*)biasv)[col1] : bf2f(((const ushort_t*)biasv)[col1]);
#pragma unroll
        for (int r = 0; r < 4; ++r) {
            size_t row = (size_t)(r0 + kq * 4 + r);
            float x0 = y0[r] + bv0; x0 = (x0 >= 0.f) ? x0 : aa * x0;
            float x1 = y1[r] + bv1; x1 = (x1 >= 0.f) ? x1 : aa * x1;
            if (is32) {
                ((float*)out)[row * OFT + col0] = x0;
                ((float*)out)[row * OFT + col1] = x1;
            } else {
                ((ushort_t*)out)[row * OFT + col0] = f2bf(x0);
                ((ushort_t*)out)[row * OFT + col1] = f2bf(x1);
            }
        }
    }
}

// ------------------------------------------------------------------- launch
extern "C" void kernel_launch(void* const* d_in, const int* in_sizes, int n_in,
                              void* d_out, int out_size, void* d_ws, size_t ws_size,
                              hipStream_t stream)
{
    const void* seq   = d_in[0];
    const void* adj   = d_in[1];
    const void* W_fc  = d_in[2];
    const void* W_q   = d_in[3];
    const void* W_k   = d_in[4];
    const void* W_v1  = d_in[5];
    const void* W_v2  = d_in[6];
    const void* a_v   = d_in[7];
    const void* a_act = d_in[8];
    const void* bias  = d_in[9];

    char* w = (char*)d_ws;
    ushort_t* regA  = (ushort_t*)w;                          // seq_fts -> ctx
    ushort_t* regKO = (ushort_t*)(w + (4u  << 20));          // kn|outb interleaved 8MB
    ushort_t* regQ  = (ushort_t*)(w + (12u << 20));          // qn 4MB
    unsigned* gcv   = (unsigned*)(w + (16u << 20));          // CSR packed 4MB
    int*      cnt   = (int*)(w + (20u << 20));               // 32KB
    float*    part  = (float*)(w + (20u << 20) + 32768);     // 2KB
    ushort_t* Wp    = (ushort_t*)(w + (21u << 20));          // 768KB frag weights

    k0_prep<<<192, 256, 0, stream>>>(W_fc, W_q, W_k, W_v1, W_v2, Wp);
    k1_extract_fc<<<NBLK, 1024, 0, stream>>>(seq, adj, W_fc, Wp, regA, gcv, cnt);
    k2_spmm_qk<<<NBLK, 512, 0, stream>>>(regA, regKO, regQ, Wp, gcv, cnt, part);
    k3a_attn<<<1024, 512, 0, stream>>>(regKO, regQ, regA, gcv, cnt);
    k3b_v<<<NBLK, 512, 0, stream>>>(regA, Wp, W_fc, a_v, a_act, bias, part, d_out);
}